// Round 2
// baseline (248.247 us; speedup 1.0000x reference)
//
#include <hip/hip_runtime.h>
#include <math.h>

#define B_ 256
#define N_ 128
#define D_ 128
#define L_ 32
#define E_ 262144
#define PW_ 254          // bitmap words per graph = 8128/32
#define DCAP 96          // per-node neighbor capacity (max deg ~40 expected)

// workspace layout (u32 units)
#define NDEG_OFF 0               // 32768 u32 per-node degree counters
#define BM_OFF   32768           // 65024 u32 pair-target bitmap
#define KLS_OFF  97792           // 256 f32 per-graph KL sums
#define LP_OFF   98048           // 256 f32 per-graph log_prob sums
#define DONE_OFF 98304           // 16 u32 (ticket counter + pad)
#define ADJ_OFF  98320           // 32768*96 u8 CSR neighbor lists (786432 u32)
#define Z_OFF    884752          // 32768*32 f32 latents
#define ZERO_WORDS 98320         // ndeg + bitmap + kls + logp + ticket

// ---------------------------------------------------------------------------
// Per-edge: CSR adjacency build (atomics over 32768 node counters) + bitmap.
__global__ __launch_bounds__(256) void k_build(
    const int* __restrict__ ei, unsigned* __restrict__ ndeg,
    unsigned char* __restrict__ adj, unsigned* __restrict__ bm)
{
    int e = blockIdx.x * 256 + threadIdx.x;
    int src = ei[e], dst = ei[E_ + e];
    unsigned s1 = atomicAdd(&ndeg[src], 1u);
    if (s1 < DCAP) adj[(size_t)src * DCAP + s1] = (unsigned char)(dst & 127);
    unsigned s2 = atomicAdd(&ndeg[dst], 1u);
    if (s2 < DCAP) adj[(size_t)dst * DCAP + s2] = (unsigned char)(src & 127);
    int li = src & 127, lj = dst & 127, g = src >> 7;
    int p = li * (255 - li) / 2 + (lj - li - 1);
    atomicOr(&bm[g * PW_ + (p >> 5)], 1u << (p & 31));
}

// ---------------------------------------------------------------------------
// Fused gather+encoder. Round-10: revert round-9's direct-global W reads
// (measured regression: L2 latency exposed per k-step, VALUBusy 43->32).
// W is back in LDS but now staged T14-style: 12 stages of 8 KB (W1 = 8
// chunks x 16 rows, WB = 4 chunks x 32 rows), double-buffered in 16 KB.
// Stage s+2 global loads issue into 8 VGPRs at the top of stage-s compute
// and commit to LDS one full compute phase later, so every vmcnt drain at
// a barrier finds loads that had ~900 cycles to land. Stage 0 issues
// before the gather. LDS = 16896 + 16384 = 33280 B -> 4 blk/CU (proven).
__global__ __launch_bounds__(256, 4) void k_encoder(
    const float* __restrict__ x, const unsigned* __restrict__ ndeg,
    const unsigned char* __restrict__ adj,
    const float* __restrict__ W1, const float* __restrict__ b1,
    const float* __restrict__ Wmu, const float* __restrict__ bmu,
    const float* __restrict__ Wls, const float* __restrict__ bls,
    const float* __restrict__ eps,
    float* __restrict__ z, float* __restrict__ kls)
{
    __shared__ float XAs[32 * 132];   // 16896 B; reused as HS after GEMM1
    __shared__ float Ws[2][2048];     // 2 x 8192 B double-buffered W stage
    int t = threadIdx.x;
    int g = blockIdx.x & 255;         // graph (fixes XCD: g % 8)
    int quar = blockIdx.x >> 8;       // 0..3
    int row0 = g * 128 + quar * 32;
    int rg = t >> 5;                  // 0..7
    int cg = t & 31;                  // 0..31
    int lane = t & 63;

    float4 pre0, pre1;                // in-flight stage (8 VGPR)
    auto issueW1 = [&](int s) {       // stage s<8: W1 rows 16s..16s+15
        const float4* gp = (const float4*)(W1 + s * 2048);
        pre0 = gp[t];
        pre1 = gp[t + 256];
    };
    auto issueWB = [&](int ch) {      // stage 8+ch: [Wmu|Wls] rows 32ch..+31
        {
            int c5 = t, row = c5 >> 4, col4 = (c5 & 15) << 2;
            int rowg = ch * 32 + row;
            pre0 = (col4 < 32) ? *(const float4*)(Wmu + rowg * 32 + col4)
                               : *(const float4*)(Wls + rowg * 32 + col4 - 32);
        }
        {
            int c5 = t + 256, row = c5 >> 4, col4 = (c5 & 15) << 2;
            int rowg = ch * 32 + row;
            pre1 = (col4 < 32) ? *(const float4*)(Wmu + rowg * 32 + col4)
                               : *(const float4*)(Wls + rowg * 32 + col4 - 32);
        }
    };
    auto commit = [&](int buf) {      // regs -> LDS buffer
        ((float4*)Ws[buf])[t] = pre0;
        ((float4*)Ws[buf])[t + 256] = pre1;
    };

    issueW1(0);                       // hide stage-0 load under the gather

    // ---- phase G: gather 32 XA rows; 2 passes x 16 nodes, 16 thr/node ----
    {
        int nidx = t >> 4;            // 0..15
        int fo = (t & 15) * 8;        // float offset 0..120
        for (int p = 0; p < 2; ++p) {
            int lrow = p * 16 + nidx;
            int gnode = row0 + lrow;
            const float* xr = x + (size_t)gnode * 128 + fo;
            float4 a0 = *(const float4*)xr;
            float4 a1 = *(const float4*)(xr + 4);
            int deg = (int)ndeg[gnode];
            if (deg > DCAP) deg = DCAP;
            const unsigned char* al = adj + (size_t)gnode * DCAP;
            const float* gx = x + (size_t)(gnode & ~127) * 128 + fo;
            int e = 0;
            for (; e + 4 <= deg; e += 4) {
                unsigned pk = *(const unsigned*)(al + e);
                const float* r0 = gx + (pk & 255u) * 128;
                const float* r1 = gx + ((pk >> 8) & 255u) * 128;
                const float* r2 = gx + ((pk >> 16) & 255u) * 128;
                const float* r3 = gx + (pk >> 24) * 128;
                float4 v00 = *(const float4*)r0, v01 = *(const float4*)(r0 + 4);
                float4 v10 = *(const float4*)r1, v11 = *(const float4*)(r1 + 4);
                float4 v20 = *(const float4*)r2, v21 = *(const float4*)(r2 + 4);
                float4 v30 = *(const float4*)r3, v31 = *(const float4*)(r3 + 4);
                a0.x += v00.x + v10.x + v20.x + v30.x;
                a0.y += v00.y + v10.y + v20.y + v30.y;
                a0.z += v00.z + v10.z + v20.z + v30.z;
                a0.w += v00.w + v10.w + v20.w + v30.w;
                a1.x += v01.x + v11.x + v21.x + v31.x;
                a1.y += v01.y + v11.y + v21.y + v31.y;
                a1.z += v01.z + v11.z + v21.z + v31.z;
                a1.w += v01.w + v11.w + v21.w + v31.w;
            }
            for (; e < deg; ++e) {
                const float* r = gx + (unsigned)al[e] * 128;
                float4 v0 = *(const float4*)r, v1 = *(const float4*)(r + 4);
                a0.x += v0.x; a0.y += v0.y; a0.z += v0.z; a0.w += v0.w;
                a1.x += v1.x; a1.y += v1.y; a1.z += v1.z; a1.w += v1.w;
            }
            *(float4*)(XAs + lrow * 132 + fo) = a0;
            *(float4*)(XAs + lrow * 132 + fo + 4) = a1;
        }
    }

    commit(0);                        // stage0 regs -> buf0 (pre-barrier)
    issueW1(1);
    __syncthreads();                  // XAs + buf0 visible

    // ---- phase 1: h = relu(XA @ W1 + b1); 8 chunks, dbuf prefetch ----
    float acc[4][4];
    #pragma unroll
    for (int i = 0; i < 4; ++i)
        #pragma unroll
        for (int j = 0; j < 4; ++j) acc[i][j] = 0.f;

    #pragma unroll
    for (int c = 0; c < 8; ++c) {
        if (c) __syncthreads();       // stage c (committed at iter c-1) visible
        if (c < 7) commit((c + 1) & 1);
        if (c < 6)      issueW1(c + 2);
        else if (c == 6) issueWB(0);      // pre <- stage 8
        else { commit(0); issueWB(1); }   // c==7: stage8 -> buf0; pre <- stage 9
        const float* Wb = Ws[c & 1];
        #pragma unroll
        for (int k = 0; k < 16; k += 4) {
            float4 av[4], wv[4];
            #pragma unroll
            for (int i = 0; i < 4; ++i)
                av[i] = *(const float4*)(XAs + (4 * rg + i) * 132 + c * 16 + k);
            #pragma unroll
            for (int dk = 0; dk < 4; ++dk)
                wv[dk] = *(const float4*)(Wb + (k + dk) * 128 + 4 * cg);
            #pragma unroll
            for (int i = 0; i < 4; ++i) {
                acc[i][0] += av[i].x * wv[0].x + av[i].y * wv[1].x + av[i].z * wv[2].x + av[i].w * wv[3].x;
                acc[i][1] += av[i].x * wv[0].y + av[i].y * wv[1].y + av[i].z * wv[2].y + av[i].w * wv[3].y;
                acc[i][2] += av[i].x * wv[0].z + av[i].y * wv[1].z + av[i].z * wv[2].z + av[i].w * wv[3].z;
                acc[i][3] += av[i].x * wv[0].w + av[i].y * wv[1].w + av[i].z * wv[2].w + av[i].w * wv[3].w;
            }
        }
    }

    // relu+bias -> HS written into same rows (wave-private rows)
    {
        float4 bb = *(const float4*)(b1 + 4 * cg);
        #pragma unroll
        for (int i = 0; i < 4; ++i) {
            float4 h;
            h.x = fmaxf(acc[i][0] + bb.x, 0.f);
            h.y = fmaxf(acc[i][1] + bb.y, 0.f);
            h.z = fmaxf(acc[i][2] + bb.z, 0.f);
            h.w = fmaxf(acc[i][3] + bb.w, 0.f);
            *(float4*)(XAs + (4 * rg + i) * 132 + 4 * cg) = h;
        }
    }
    __syncthreads();                  // HS + stage8(buf0) visible

    // ---- phase 2: [mu|ls] = h @ WB + bias; 4 chunks, dbuf prefetch ----
    float a3[4][2];
    #pragma unroll
    for (int i = 0; i < 4; ++i) { a3[i][0] = 0.f; a3[i][1] = 0.f; }

    #pragma unroll
    for (int c2 = 0; c2 < 4; ++c2) {
        if (c2) __syncthreads();      // stage 8+c2 visible
        if (c2 < 3) commit((c2 + 1) & 1);  // stage 9+c2 -> buf (9+c2)&1
        if (c2 < 2) issueWB(2 + c2);
        const float* Wb = Ws[c2 & 1];
        #pragma unroll
        for (int k = 0; k < 32; k += 4) {
            float4 av[4];
            float2 wv[4];
            #pragma unroll
            for (int i = 0; i < 4; ++i)
                av[i] = *(const float4*)(XAs + (4 * rg + i) * 132 + c2 * 32 + k);
            #pragma unroll
            for (int dk = 0; dk < 4; ++dk)
                wv[dk] = *(const float2*)(Wb + (k + dk) * 64 + 2 * cg);
            #pragma unroll
            for (int i = 0; i < 4; ++i) {
                a3[i][0] += av[i].x * wv[0].x + av[i].y * wv[1].x + av[i].z * wv[2].x + av[i].w * wv[3].x;
                a3[i][1] += av[i].x * wv[0].y + av[i].y * wv[1].y + av[i].z * wv[2].y + av[i].w * wv[3].y;
            }
        }
    }
    {
        float2 bv = (cg < 16) ? *(const float2*)(bmu + 2 * cg)
                              : *(const float2*)(bls + 2 * cg - 32);
        #pragma unroll
        for (int i = 0; i < 4; ++i) { a3[i][0] += bv.x; a3[i][1] += bv.y; }
    }

    // exchange mu<->ls with partner lane (cg ^ 16)
    float o3[4][2];
    #pragma unroll
    for (int i = 0; i < 4; ++i) {
        o3[i][0] = __shfl_xor(a3[i][0], 16);
        o3[i][1] = __shfl_xor(a3[i][1], 16);
    }

    // ---- phase 3: z = mu + exp(ls)*eps, KL; wave shfl-reduce, 1 atomic ----
    float klsum = 0.f;
    if (cg < 16) {                    // this lane holds mu; partner held ls
        int lo = cg;
        #pragma unroll
        for (int i = 0; i < 4; ++i) {
            int rowg = row0 + 4 * rg + i;
            float mu0 = a3[i][0], mu1 = a3[i][1];
            float ls0 = o3[i][0], ls1 = o3[i][1];
            float2 ev = *(const float2*)(eps + (size_t)rowg * 32 + 2 * lo);
            float s0 = __expf(ls0), s1 = __expf(ls1);
            float2 zv = make_float2(mu0 + s0 * ev.x, mu1 + s1 * ev.y);
            *(float2*)(z + (size_t)rowg * 32 + 2 * lo) = zv;
            klsum += s0 * s0 + mu0 * mu0 - 1.f - 2.f * ls0
                   + s1 * s1 + mu1 * mu1 - 1.f - 2.f * ls1;
        }
    }
    #pragma unroll
    for (int off = 32; off > 0; off >>= 1) klsum += __shfl_xor(klsum, off);
    if (lane == 0) atomicAdd(&kls[g], 0.5f * klsum);
}

// ---------------------------------------------------------------------------
// Decoder: 4 blocks per graph (i-quarters), XCD-swizzled; shfl-reduce +
// one atomic per wave; fast-math softplus. Final ELBO reduction folded in
// via last-block-done ticket (saves the k_finalize launch); the
// __syncthreads before the ticket drains this block's logp atomics to the
// device-coherent point (compiler emits vmcnt(0) before s_barrier).
__global__ __launch_bounds__(256) void k_decoder(
    const float* __restrict__ z, const unsigned* __restrict__ bitmap,
    float* __restrict__ logp, const float* __restrict__ kls,
    unsigned* __restrict__ done, float* __restrict__ out)
{
    __shared__ float zT[32 * 132];
    __shared__ unsigned bm[PW_];
    __shared__ unsigned lastflag;
    int b = blockIdx.x & 255, quar = blockIdx.x >> 8, t = threadIdx.x;

    #pragma unroll
    for (int i = 0; i < 16; ++i) {
        int c = t + i * 256;
        int n = c >> 5, l = c & 31;
        zT[l * 132 + n] = z[((size_t)b * N_ + n) * L_ + l];
    }
    if (t < PW_) bm[t] = bitmap[b * PW_ + t];
    __syncthreads();

    int i0 = quar * 32 + ((t >> 5) << 2);
    int j0 = (t & 31) << 2;
    float gacc[4][4];
    #pragma unroll
    for (int a = 0; a < 4; ++a)
        #pragma unroll
        for (int c = 0; c < 4; ++c) gacc[a][c] = 0.f;

    #pragma unroll 4
    for (int l = 0; l < 32; ++l) {
        float4 a0 = *(const float4*)(zT + l * 132 + i0);
        float4 b0 = *(const float4*)(zT + l * 132 + j0);
        float za[4] = {a0.x, a0.y, a0.z, a0.w};
        float zb[4] = {b0.x, b0.y, b0.z, b0.w};
        #pragma unroll
        for (int a = 0; a < 4; ++a)
            #pragma unroll
            for (int c = 0; c < 4; ++c) gacc[a][c] += za[a] * zb[c];
    }

    float sum = 0.f;
    #pragma unroll
    for (int a = 0; a < 4; ++a) {
        int i = i0 + a;
        #pragma unroll
        for (int c = 0; c < 4; ++c) {
            int j = j0 + c;
            if (j > i) {
                float lg = gacc[a][c];
                int p = i * (255 - i) / 2 + (j - i - 1);
                unsigned bit = (bm[p >> 5] >> (p & 31)) & 1u;
                float sp = __logf(1.f + __expf(-fabsf(lg))) + fmaxf(lg, 0.f);
                sum += bit ? (lg - sp) : (-sp);
            }
        }
    }
    #pragma unroll
    for (int off = 32; off > 0; off >>= 1) sum += __shfl_xor(sum, off);
    if ((t & 63) == 0) atomicAdd(&logp[b], sum);

    // ---- last-block-done: fold the final ELBO reduction into this kernel
    __syncthreads();                  // drains this block's atomics (vmcnt)
    if (t == 0) {
        unsigned prev = atomicAdd(done, 1u);
        lastflag = (prev == 4u * B_ - 1u) ? 1u : 0u;
    }
    __syncthreads();
    if (lastflag) {
        float v = __hip_atomic_load(&logp[t], __ATOMIC_RELAXED, __HIP_MEMORY_SCOPE_AGENT)
                - __hip_atomic_load(&kls[t],  __ATOMIC_RELAXED, __HIP_MEMORY_SCOPE_AGENT);
        zT[t] = v;
        __syncthreads();
        for (int s = 128; s > 0; s >>= 1) {
            if (t < s) zT[t] += zT[t + s];
            __syncthreads();
        }
        if (t == 0) out[0] = -zT[0] * (1.0f / 256.0f);
    }
}

// ---------------------------------------------------------------------------
extern "C" void kernel_launch(void* const* d_in, const int* in_sizes, int n_in,
                              void* d_out, int out_size, void* d_ws, size_t ws_size,
                              hipStream_t stream) {
    const float* x   = (const float*)d_in[0];
    const int*   ei  = (const int*)d_in[1];
    // d_in[2] = batch (unused; block-contiguous layout known)
    const float* eps = (const float*)d_in[3];
    const float* W1  = (const float*)d_in[4];
    const float* b1  = (const float*)d_in[5];
    const float* Wmu = (const float*)d_in[6];
    const float* bmu = (const float*)d_in[7];
    const float* Wls = (const float*)d_in[8];
    const float* bls = (const float*)d_in[9];

    unsigned* wsw = (unsigned*)d_ws;
    unsigned*      ndeg = wsw + NDEG_OFF;
    unsigned*      bm   = wsw + BM_OFF;
    float*         kls  = (float*)(wsw + KLS_OFF);
    float*         logp = (float*)(wsw + LP_OFF);
    unsigned*      done = wsw + DONE_OFF;
    unsigned char* adj  = (unsigned char*)(wsw + ADJ_OFF);
    float*         z    = (float*)(wsw + Z_OFF);

    hipMemsetAsync(d_ws, 0, ZERO_WORDS * sizeof(unsigned), stream);

    k_build   <<<E_ / 256, 256, 0, stream>>>(ei, ndeg, adj, bm);
    k_encoder <<<1024, 256, 0, stream>>>(x, ndeg, adj, W1, b1, Wmu, bmu,
                                         Wls, bls, eps, z, kls);
    k_decoder <<<4 * B_, 256, 0, stream>>>(z, bm, logp, kls, done, (float*)d_out);
}